// Round 7
// baseline (144.789 us; speedup 1.0000x reference)
//
#include <hip/hip_runtime.h>

#define NPTS 8192
#define NTOT 16384
#define KNB 11
#define CAP 16
#define MARG 9.0f

typedef __attribute__((ext_vector_type(8))) short short8;
typedef __attribute__((ext_vector_type(4))) float f32x4;

__device__ __forceinline__ unsigned short f2bf(float x) {
  union { float f; unsigned u; } v; v.f = x;
  unsigned r = v.u + 0x7FFFu + ((v.u >> 16) & 1u);
  return (unsigned short)(r >> 16);
}

__device__ __forceinline__ float sigm(float x) { return 1.f / (1.f + expf(-x)); }

// ---------------- K0: W12 = W1*W2, b12 = b1*W2 + b2 ; zero cnt ----------------
__global__ __launch_bounds__(256) void k0_w12(
    const float* __restrict__ W1, const float* __restrict__ b1,
    const float* __restrict__ W2, const float* __restrict__ b2,
    float* __restrict__ W12, float* __restrict__ b12,
    unsigned* __restrict__ cnt) {
  int t = blockIdx.x * 256 + threadIdx.x;   // 64 blocks -> 16384
  cnt[t] = 0u;
  if (t >= 4096) return;
  int d = t >> 6, e = t & 63;
  float s = 0.f;
  for (int kk = 0; kk < 64; ++kk) s = fmaf(W1[d * 64 + kk], W2[kk * 64 + e], s);
  W12[t] = s;
  if (d == 0) {
    float sb = b2[e];
    for (int kk = 0; kk < 64; ++kk) sb = fmaf(b1[kk], W2[kk * 64 + e], sb);
    b12[e] = sb;
  }
}

// ---------------- K1: f = p^T*W12 + b12 ; sq/sq32 ; bf16 prefilter copy ----------------
// 256 blocks x 256 threads: 64 points/block, wave w handles dims e0=w*16..+16.
// p tile staged in LDS (coalesced); W12 via wave-uniform offset -> s_load path.
__global__ __launch_bounds__(256) void k1_encode(
    const float* __restrict__ p,      // [2][64][NPTS]
    const float* __restrict__ W12,    // [64][64]
    const float* __restrict__ b12,    // [64]
    float* __restrict__ f32f,         // [NTOT][64]
    unsigned short* __restrict__ fpre,// [NTOT][32] bf16 (dims 0..31)
    float* __restrict__ sq,           // [NTOT] full 64-dim |f|^2
    float* __restrict__ sq32) {       // [NTOT] dims 0..31 |f|^2
  __shared__ float sp[64 * 64];       // 16 KB: sp[d*64 + n_local]
  __shared__ float sPart[4][64];
  int t = threadIdx.x, lane = t & 63;
  int w = __builtin_amdgcn_readfirstlane(t >> 6);
  int e0 = w * 16;                          // wave-uniform -> scalar loads
  int base = blockIdx.x * 64;
  int b = base >> 13, n0 = base & (NPTS - 1);
  const float* pb = p + (size_t)b * 64 * NPTS + n0;

  // stage p tile: 64 d-rows x 64 points, coalesced uint4
  int row = t >> 4, chunk = t & 15;
#pragma unroll
  for (int k = 0; k < 4; ++k) {
    int r = k * 16 + row;
    uint4 v = *(const uint4*)(pb + (size_t)r * NPTS + chunk * 4);
    *(uint4*)(sp + r * 64 + chunk * 4) = v;
  }
  __syncthreads();

  float f[16];
#pragma unroll
  for (int j = 0; j < 16; ++j) f[j] = b12[e0 + j];

#pragma unroll 8
  for (int d = 0; d < 64; ++d) {
    float pd = sp[d * 64 + lane];
#pragma unroll
    for (int j = 0; j < 16; ++j)
      f[j] = fmaf(pd, W12[d * 64 + e0 + j], f[j]);
  }

  float s = 0.f;
#pragma unroll
  for (int j = 0; j < 16; ++j) s = fmaf(f[j], f[j], s);
  sPart[w][lane] = s;
  __syncthreads();
  if (w == 0) {
    float s32 = sPart[0][lane] + sPart[1][lane];
    float s64 = s32 + (sPart[2][lane] + sPart[3][lane]);
    sq32[base + lane] = s32;
    sq[base + lane] = s64;
  }

  f32x4* o4 = (f32x4*)(f32f + (size_t)(base + lane) * 64 + e0);
#pragma unroll
  for (int jj = 0; jj < 4; ++jj) {
    f32x4 v; v[0] = f[4 * jj]; v[1] = f[4 * jj + 1]; v[2] = f[4 * jj + 2]; v[3] = f[4 * jj + 3];
    o4[jj] = v;
  }
  if (w < 2) {                               // dims 0..31 -> bf16 prefilter
    unsigned* ob = (unsigned*)(fpre + (size_t)(base + lane) * 32 + e0);
#pragma unroll
    for (int jj = 0; jj < 8; ++jj) {
      unsigned lo = f2bf(f[2 * jj]);
      unsigned hi = f2bf(f[2 * jj + 1]);
      ob[jj] = lo | (hi << 16);
    }
  }
}

// ---------------- K2: 32-dim prefilter Gram, triangle-symmetric ----
// 1056 blocks = 2 x 528 (lower-triangle incl diag of 32x32 256-blocks).
// Hot: per tile 1 ds_read + 4 MFMA + EXACT per-row/col margin test -> SGPR hitmask.
// Cold (once, after loop): recompute only hit tiles (diag: 4/16; off-diag: ~never).
__global__ __launch_bounds__(256) void k2_gram_select(
    const unsigned short* __restrict__ fpre, // [NTOT][32]
    const float* __restrict__ sq32,          // [NTOT]
    unsigned* __restrict__ cnt,              // [NTOT]
    unsigned* __restrict__ cand) {           // [NTOT][CAP]
  __shared__ uint4 sB[1024];                 // 16 KB panel, XOR-swizzled
  int bid = blockIdx.x;
  int b = (bid >= 528) ? 1 : 0;
  int rem = bid - b * 528;
  int band = (int)((sqrtf(8.f * (float)rem + 1.f) - 1.f) * 0.5f);
  if (((band + 1) * (band + 2)) / 2 <= rem) band++;
  else if ((band * (band + 1)) / 2 > rem) band--;
  int seg = rem - (band * (band + 1)) / 2;

  int t = threadIdx.x;
  int lane = t & 63;
  int arow = lane & 15;
  int q = lane >> 4;
  int wave = t >> 6;
  int rowbase = band * 256 + wave * 64;
  int cbase = seg * 256;
  const unsigned short* fb = fpre + (size_t)b * NPTS * 32;
  const float* s32b = sq32 + b * NPTS;

  // ---- prologue: all global loads, then ONE barrier ----
  const uint4* gsrc = (const uint4*)fb + (size_t)seg * 1024;
  uint4 v[4];
#pragma unroll
  for (int k = 0; k < 4; ++k) v[k] = gsrc[t + k * 256];

  short8 afrag[4];
#pragma unroll
  for (int tr = 0; tr < 4; ++tr)
    afrag[tr] = *(const short8*)(fb + (size_t)(rowbase + tr * 16 + arow) * 32 + q * 8);

  f32x4 srq[4], hh[4];
#pragma unroll
  for (int tr = 0; tr < 4; ++tr) {
    srq[tr] = *(const f32x4*)(s32b + rowbase + tr * 16 + (q << 2));
    hh[tr] = 0.5f * srq[tr];
  }
  float thrc[16];                            // per-lane column threshold
#pragma unroll
  for (int cc = 0; cc < 4; ++cc)
#pragma unroll
    for (int tc = 0; tc < 4; ++tc)
      thrc[cc * 4 + tc] = 0.5f * s32b[cbase + cc * 64 + tc * 16 + arow] - 0.5f * MARG;

#pragma unroll
  for (int k = 0; k < 4; ++k) {
    int c = t + k * 256;
    int r = c >> 2, qq = c & 3;
    sB[r * 4 + (qq ^ (r & 3))] = v[k];
  }
  __syncthreads();   // the ONLY barrier

  // ---- hot pass: MFMA + exact margin test, hit tiles -> SGPR mask ----
  f32x4 z4 = {0.f, 0.f, 0.f, 0.f};
  unsigned hitmask = 0u;
#pragma unroll
  for (int cc = 0; cc < 4; ++cc)
#pragma unroll
    for (int tc = 0; tc < 4; ++tc) {
      int e = cc * 4 + tc;
      int rl = cc * 64 + tc * 16 + arow;
      short8 bf = *(const short8*)&sB[rl * 4 + (q ^ (rl & 3))];
      f32x4 a0 = __builtin_amdgcn_mfma_f32_16x16x32_bf16(afrag[0], bf, z4, 0, 0, 0);
      f32x4 a1 = __builtin_amdgcn_mfma_f32_16x16x32_bf16(afrag[1], bf, z4, 0, 0, 0);
      f32x4 a2 = __builtin_amdgcn_mfma_f32_16x16x32_bf16(afrag[2], bf, z4, 0, 0, 0);
      f32x4 a3 = __builtin_amdgcn_mfma_f32_16x16x32_bf16(afrag[3], bf, z4, 0, 0, 0);
      // exact: exists row with a - 0.5*sq_row > 0.5*sq_col - MARG/2  <=>  d2_32 < MARG
      float m0 = fmaxf(fmaxf(a0[0] - hh[0][0], a0[1] - hh[0][1]),
                       fmaxf(a0[2] - hh[0][2], a0[3] - hh[0][3]));
      float m1 = fmaxf(fmaxf(a1[0] - hh[1][0], a1[1] - hh[1][1]),
                       fmaxf(a1[2] - hh[1][2], a1[3] - hh[1][3]));
      float m2 = fmaxf(fmaxf(a2[0] - hh[2][0], a2[1] - hh[2][1]),
                       fmaxf(a2[2] - hh[2][2], a2[3] - hh[2][3]));
      float m3 = fmaxf(fmaxf(a3[0] - hh[3][0], a3[1] - hh[3][1]),
                       fmaxf(a3[2] - hh[3][2], a3[3] - hh[3][3]));
      float m = fmaxf(fmaxf(m0, m1), fmaxf(m2, m3));
      if (__ballot(m > thrc[e])) hitmask |= (1u << e);
    }

  // ---- cold: only hit tiles (compact, single copy of capture code) ----
  if (hitmask) {
#pragma unroll 1
    for (int e = 0; e < 16; ++e) {
      if (!(hitmask & (1u << e))) continue;
      int cc = e >> 2, tc = e & 3;
      int rl = cc * 64 + tc * 16 + arow;
      short8 bf = *(const short8*)&sB[rl * 4 + (q ^ (rl & 3))];
      int colpt = cbase + cc * 64 + tc * 16 + arow;
      float scv = s32b[colpt];
      f32x4 acc[4];
#pragma unroll
      for (int tr = 0; tr < 4; ++tr)
        acc[tr] = __builtin_amdgcn_mfma_f32_16x16x32_bf16(afrag[tr], bf, z4, 0, 0, 0);
#pragma unroll
      for (int tr = 0; tr < 4; ++tr)
#pragma unroll
        for (int rg = 0; rg < 4; ++rg) {
          float d2 = srq[tr][rg] + scv - 2.f * acc[tr][rg];
          if (d2 < MARG) {
            int rowpt = rowbase + tr * 16 + (q << 2) + rg;
            int gr = b * NPTS + rowpt;
            union { float f; unsigned u; } cv; cv.f = d2 + 16.f;  // monotone bits
            unsigned kb = cv.u & 0xFFFFE000u;
            unsigned slot = atomicAdd(&cnt[gr], 1u);
            if (slot < CAP) cand[gr * CAP + slot] = kb | (unsigned)colpt;
            if (band != seg) {
              int gc = b * NPTS + colpt;
              unsigned slot2 = atomicAdd(&cnt[gc], 1u);
              if (slot2 < CAP) cand[gc * CAP + slot2] = kb | (unsigned)rowpt;
            }
          }
        }
    }
  }
}

// ---------------- K_tail: fused refine + 5 mean-field iterations ----------------
// 2 blocks (one per batch) x 1024 threads; q lives in LDS; W/IDX staged via global
// (L2-resident, written and read by the same block).
__global__ __launch_bounds__(1024) void k_tail(
    const float* __restrict__ f32f, const float* __restrict__ sq,
    const unsigned* __restrict__ cnt, const unsigned* __restrict__ cand,
    float* __restrict__ Wbuf, int* __restrict__ IDXb,
    const float* __restrict__ logits, float* __restrict__ out) {
  __shared__ float qs[NPTS];                // 32 KB
  int t = threadIdx.x;
  int rb = blockIdx.x * NPTS;
  int bb = blockIdx.x;
  float lg[8];
  unsigned c[8];

  // ---- phase A: init q0 + refine rows with >1 candidate (exact f32) ----
#pragma unroll 1
  for (int j = 0; j < 8; ++j) {
    int il = j * 1024 + t;
    int r = rb + il;
    lg[j] = logits[r];
    qs[il] = sigm(lg[j]);
    unsigned count = cnt[r];
    c[j] = count;
    if (count > CAP) count = CAP;
    if (count > 1) {
      unsigned k[CAP];
#pragma unroll
      for (int jj = 0; jj < CAP; ++jj)
        k[jj] = (jj < (int)count) ? cand[r * CAP + jj] : 0xFFFFFFFFu;
#pragma unroll
      for (int a = 0; a < CAP - 1; ++a)
#pragma unroll
        for (int cc = 0; cc < CAP - 1; ++cc) {
          unsigned lo = min(k[cc], k[cc + 1]);
          unsigned hi = max(k[cc], k[cc + 1]);
          k[cc] = lo; k[cc + 1] = hi;
        }
      float fr[64];
      const f32x4* fr4 = (const f32x4*)(f32f + (size_t)r * 64);
#pragma unroll
      for (int jj = 0; jj < 16; ++jj) {
        f32x4 v = fr4[jj];
        fr[4 * jj] = v[0]; fr[4 * jj + 1] = v[1]; fr[4 * jj + 2] = v[2]; fr[4 * jj + 3] = v[3];
      }
      float sqr = sq[r];
      int nsel = (int)count < KNB ? (int)count : KNB;
#pragma unroll 1
      for (int kk = 0; kk < KNB; ++kk) {
        float w = 0.f;
        int gi = r;
        if (kk < nsel) {
          int col = (int)(k[kk] & 8191u);
          gi = bb * NPTS + col;
          const float* fm = f32f + (size_t)gi * 64;
          float dot = 0.f;
#pragma unroll
          for (int d = 0; d < 64; ++d) dot = fmaf(fr[d], fm[d], dot);
          float d2 = sqr + sq[gi] - 2.f * dot;
          w = expf(-d2);
        }
        Wbuf[(size_t)r * KNB + kk] = w;
        IDXb[(size_t)r * KNB + kk] = gi;
      }
    }
  }
  __threadfence();
  __syncthreads();

  // ---- phase B: 5 mean-field iterations ----
  float u[8];
  for (int it = 0; it < 5; ++it) {
#pragma unroll
    for (int j = 0; j < 8; ++j) {
      int il = j * 1024 + t;
      float msg;
      if (c[j] <= 1u) {
        msg = qs[il];                        // self weight is exactly 1
      } else {
        msg = 0.f;
        const float* wp = Wbuf + (size_t)(rb + il) * KNB;
        const int* ip = IDXb + (size_t)(rb + il) * KNB;
#pragma unroll
        for (int kk = 0; kk < KNB; ++kk) msg = fmaf(wp[kk], qs[ip[kk] - rb], msg);
      }
      u[j] = lg[j] - msg;
    }
    __syncthreads();
#pragma unroll
    for (int j = 0; j < 8; ++j) qs[j * 1024 + t] = sigm(u[j]);
    __syncthreads();
  }
#pragma unroll
  for (int j = 0; j < 8; ++j) out[rb + j * 1024 + t] = sigm(u[j]);
}

// ---------------- launch ----------------
extern "C" void kernel_launch(void* const* d_in, const int* in_sizes, int n_in,
                              void* d_out, int out_size, void* d_ws, size_t ws_size,
                              hipStream_t stream) {
  const float* logits = (const float*)d_in[0]; // [2][8192]
  const float* p      = (const float*)d_in[1]; // [2][64][8192]
  const float* W1     = (const float*)d_in[2];
  const float* b1     = (const float*)d_in[3];
  const float* W2     = (const float*)d_in[4];
  const float* b2     = (const float*)d_in[5];
  float* out = (float*)d_out;                  // [2][8192]

  char* ws = (char*)d_ws;
  float* W12 = (float*)ws;                                         // 4096 f
  float* b12 = W12 + 4096;                                         // 64 f
  float* f32f = b12 + 64;                                          // NTOT*64 f
  unsigned short* fpre = (unsigned short*)(f32f + (size_t)NTOT * 64); // NTOT*32 bf16
  float* sq = (float*)(fpre + (size_t)NTOT * 32);                  // NTOT f
  float* sq32 = sq + NTOT;                                         // NTOT f
  unsigned* cnt = (unsigned*)(sq32 + NTOT);                        // NTOT u32
  unsigned* cand = cnt + NTOT;                                     // NTOT*CAP u32
  float* Wbuf = (float*)(cand + (size_t)NTOT * CAP);               // NTOT*11 f
  int* IDX = (int*)(Wbuf + (size_t)NTOT * KNB);                    // NTOT*11 i32

  k0_w12<<<64, 256, 0, stream>>>(W1, b1, W2, b2, W12, b12, cnt);
  k1_encode<<<256, 256, 0, stream>>>(p, W12, b12, f32f, fpre, sq, sq32);
  k2_gram_select<<<1056, 256, 0, stream>>>(fpre, sq32, cnt, cand);
  k_tail<<<2, 1024, 0, stream>>>(f32f, sq, cnt, cand, Wbuf, IDX, logits, out);
}

// Round 8
// 124.988 us; speedup vs baseline: 1.1584x; 1.1584x over previous
//
#include <hip/hip_runtime.h>

#define NPTS 8192
#define NTOT 16384
#define KNB 11
#define CAP 16
#define MARG 9.0f
#define MAXM 8192

typedef __attribute__((ext_vector_type(8))) short short8;
typedef __attribute__((ext_vector_type(4))) float f32x4;

__device__ __forceinline__ unsigned short f2bf(float x) {
  union { float f; unsigned u; } v; v.f = x;
  unsigned r = v.u + 0x7FFFu + ((v.u >> 16) & 1u);
  return (unsigned short)(r >> 16);
}

__device__ __forceinline__ float sigm(float x) { return 1.f / (1.f + expf(-x)); }

// ---------------- K0: W12 = W1*W2, b12 = b1*W2 + b2 ; zero cnt ----------------
__global__ __launch_bounds__(256) void k0_w12(
    const float* __restrict__ W1, const float* __restrict__ b1,
    const float* __restrict__ W2, const float* __restrict__ b2,
    float* __restrict__ W12, float* __restrict__ b12,
    unsigned* __restrict__ cnt) {
  int t = blockIdx.x * 256 + threadIdx.x;   // 64 blocks -> 16384
  cnt[t] = 0u;
  if (t >= 4096) return;
  int d = t >> 6, e = t & 63;
  float s = 0.f;
  for (int kk = 0; kk < 64; ++kk) s = fmaf(W1[d * 64 + kk], W2[kk * 64 + e], s);
  W12[t] = s;
  if (d == 0) {
    float sb = b2[e];
    for (int kk = 0; kk < 64; ++kk) sb = fmaf(b1[kk], W2[kk * 64 + e], sb);
    b12[e] = sb;
  }
}

// ---------------- K1: f = p^T*W12 + b12 ; sq/sq32 ; bf16 prefilter copy ----------------
// 256 blocks x 256 threads: 64 points/block, wave w handles dims e0=w*16..+16.
// p tile staged in LDS (coalesced); W12 via wave-uniform offset -> s_load path.
__global__ __launch_bounds__(256) void k1_encode(
    const float* __restrict__ p,      // [2][64][NPTS]
    const float* __restrict__ W12,    // [64][64]
    const float* __restrict__ b12,    // [64]
    float* __restrict__ f32f,         // [NTOT][64]
    unsigned short* __restrict__ fpre,// [NTOT][32] bf16 (dims 0..31)
    float* __restrict__ sq,           // [NTOT] full 64-dim |f|^2
    float* __restrict__ sq32) {       // [NTOT] dims 0..31 |f|^2
  __shared__ float sp[64 * 64];       // 16 KB: sp[d*64 + n_local]
  __shared__ float sPart[4][64];
  int t = threadIdx.x, lane = t & 63;
  int w = __builtin_amdgcn_readfirstlane(t >> 6);
  int e0 = w * 16;                          // wave-uniform -> scalar loads
  int base = blockIdx.x * 64;
  int b = base >> 13, n0 = base & (NPTS - 1);
  const float* pb = p + (size_t)b * 64 * NPTS + n0;

  // stage p tile: 64 d-rows x 64 points, coalesced uint4
  int row = t >> 4, chunk = t & 15;
#pragma unroll
  for (int k = 0; k < 4; ++k) {
    int r = k * 16 + row;
    uint4 v = *(const uint4*)(pb + (size_t)r * NPTS + chunk * 4);
    *(uint4*)(sp + r * 64 + chunk * 4) = v;
  }
  __syncthreads();

  float f[16];
#pragma unroll
  for (int j = 0; j < 16; ++j) f[j] = b12[e0 + j];

#pragma unroll 8
  for (int d = 0; d < 64; ++d) {
    float pd = sp[d * 64 + lane];
#pragma unroll
    for (int j = 0; j < 16; ++j)
      f[j] = fmaf(pd, W12[d * 64 + e0 + j], f[j]);
  }

  float s = 0.f;
#pragma unroll
  for (int j = 0; j < 16; ++j) s = fmaf(f[j], f[j], s);
  sPart[w][lane] = s;
  __syncthreads();
  if (w == 0) {
    float s32 = sPart[0][lane] + sPart[1][lane];
    float s64 = s32 + (sPart[2][lane] + sPart[3][lane]);
    sq32[base + lane] = s32;
    sq[base + lane] = s64;
  }

  f32x4* o4 = (f32x4*)(f32f + (size_t)(base + lane) * 64 + e0);
#pragma unroll
  for (int jj = 0; jj < 4; ++jj) {
    f32x4 v; v[0] = f[4 * jj]; v[1] = f[4 * jj + 1]; v[2] = f[4 * jj + 2]; v[3] = f[4 * jj + 3];
    o4[jj] = v;
  }
  if (w < 2) {                               // dims 0..31 -> bf16 prefilter
    unsigned* ob = (unsigned*)(fpre + (size_t)(base + lane) * 32 + e0);
#pragma unroll
    for (int jj = 0; jj < 8; ++jj) {
      unsigned lo = f2bf(f[2 * jj]);
      unsigned hi = f2bf(f[2 * jj + 1]);
      ob[jj] = lo | (hi << 16);
    }
  }
}

// ---------------- K2: 32-dim prefilter Gram, triangle-symmetric ----
// 1056 blocks = 2 x 528 (lower-triangle incl diag of 32x32 256-blocks).
// Hot: per tile 1 ds_read + 4 MFMA + EXACT per-row/col margin test -> SGPR hitmask.
// Cold (once, after loop): recompute only hit tiles (diag: 4/16; off-diag: ~never).
__global__ __launch_bounds__(256) void k2_gram_select(
    const unsigned short* __restrict__ fpre, // [NTOT][32]
    const float* __restrict__ sq32,          // [NTOT]
    unsigned* __restrict__ cnt,              // [NTOT]
    unsigned* __restrict__ cand) {           // [NTOT][CAP]
  __shared__ uint4 sB[1024];                 // 16 KB panel, XOR-swizzled
  int bid = blockIdx.x;
  int b = (bid >= 528) ? 1 : 0;
  int rem = bid - b * 528;
  int band = (int)((sqrtf(8.f * (float)rem + 1.f) - 1.f) * 0.5f);
  if (((band + 1) * (band + 2)) / 2 <= rem) band++;
  else if ((band * (band + 1)) / 2 > rem) band--;
  int seg = rem - (band * (band + 1)) / 2;

  int t = threadIdx.x;
  int lane = t & 63;
  int arow = lane & 15;
  int q = lane >> 4;
  int wave = t >> 6;
  int rowbase = band * 256 + wave * 64;
  int cbase = seg * 256;
  const unsigned short* fb = fpre + (size_t)b * NPTS * 32;
  const float* s32b = sq32 + b * NPTS;

  // ---- prologue: all global loads, then ONE barrier ----
  const uint4* gsrc = (const uint4*)fb + (size_t)seg * 1024;
  uint4 v[4];
#pragma unroll
  for (int k = 0; k < 4; ++k) v[k] = gsrc[t + k * 256];

  short8 afrag[4];
#pragma unroll
  for (int tr = 0; tr < 4; ++tr)
    afrag[tr] = *(const short8*)(fb + (size_t)(rowbase + tr * 16 + arow) * 32 + q * 8);

  f32x4 srq[4], hh[4];
#pragma unroll
  for (int tr = 0; tr < 4; ++tr) {
    srq[tr] = *(const f32x4*)(s32b + rowbase + tr * 16 + (q << 2));
    hh[tr] = 0.5f * srq[tr];
  }
  float thrc[16];                            // per-lane column threshold
#pragma unroll
  for (int cc = 0; cc < 4; ++cc)
#pragma unroll
    for (int tc = 0; tc < 4; ++tc)
      thrc[cc * 4 + tc] = 0.5f * s32b[cbase + cc * 64 + tc * 16 + arow] - 0.5f * MARG;

#pragma unroll
  for (int k = 0; k < 4; ++k) {
    int c = t + k * 256;
    int r = c >> 2, qq = c & 3;
    sB[r * 4 + (qq ^ (r & 3))] = v[k];
  }
  __syncthreads();   // the ONLY barrier

  // ---- hot pass: MFMA + exact margin test, hit tiles -> SGPR mask ----
  f32x4 z4 = {0.f, 0.f, 0.f, 0.f};
  unsigned hitmask = 0u;
#pragma unroll
  for (int cc = 0; cc < 4; ++cc)
#pragma unroll
    for (int tc = 0; tc < 4; ++tc) {
      int e = cc * 4 + tc;
      int rl = cc * 64 + tc * 16 + arow;
      short8 bf = *(const short8*)&sB[rl * 4 + (q ^ (rl & 3))];
      f32x4 a0 = __builtin_amdgcn_mfma_f32_16x16x32_bf16(afrag[0], bf, z4, 0, 0, 0);
      f32x4 a1 = __builtin_amdgcn_mfma_f32_16x16x32_bf16(afrag[1], bf, z4, 0, 0, 0);
      f32x4 a2 = __builtin_amdgcn_mfma_f32_16x16x32_bf16(afrag[2], bf, z4, 0, 0, 0);
      f32x4 a3 = __builtin_amdgcn_mfma_f32_16x16x32_bf16(afrag[3], bf, z4, 0, 0, 0);
      // exact: exists row with a - 0.5*sq_row > 0.5*sq_col - MARG/2  <=>  d2_32 < MARG
      float m0 = fmaxf(fmaxf(a0[0] - hh[0][0], a0[1] - hh[0][1]),
                       fmaxf(a0[2] - hh[0][2], a0[3] - hh[0][3]));
      float m1 = fmaxf(fmaxf(a1[0] - hh[1][0], a1[1] - hh[1][1]),
                       fmaxf(a1[2] - hh[1][2], a1[3] - hh[1][3]));
      float m2 = fmaxf(fmaxf(a2[0] - hh[2][0], a2[1] - hh[2][1]),
                       fmaxf(a2[2] - hh[2][2], a2[3] - hh[2][3]));
      float m3 = fmaxf(fmaxf(a3[0] - hh[3][0], a3[1] - hh[3][1]),
                       fmaxf(a3[2] - hh[3][2], a3[3] - hh[3][3]));
      float m = fmaxf(fmaxf(m0, m1), fmaxf(m2, m3));
      if (__ballot(m > thrc[e])) hitmask |= (1u << e);
    }

  // ---- cold: only hit tiles (compact, single copy of capture code) ----
  if (hitmask) {
#pragma unroll 1
    for (int e = 0; e < 16; ++e) {
      if (!(hitmask & (1u << e))) continue;
      int cc = e >> 2, tc = e & 3;
      int rl = cc * 64 + tc * 16 + arow;
      short8 bf = *(const short8*)&sB[rl * 4 + (q ^ (rl & 3))];
      int colpt = cbase + cc * 64 + tc * 16 + arow;
      float scv = s32b[colpt];
      f32x4 acc[4];
#pragma unroll
      for (int tr = 0; tr < 4; ++tr)
        acc[tr] = __builtin_amdgcn_mfma_f32_16x16x32_bf16(afrag[tr], bf, z4, 0, 0, 0);
#pragma unroll
      for (int tr = 0; tr < 4; ++tr)
#pragma unroll
        for (int rg = 0; rg < 4; ++rg) {
          float d2 = srq[tr][rg] + scv - 2.f * acc[tr][rg];
          if (d2 < MARG) {
            int rowpt = rowbase + tr * 16 + (q << 2) + rg;
            int gr = b * NPTS + rowpt;
            union { float f; unsigned u; } cv; cv.f = d2 + 16.f;  // monotone bits
            unsigned kb = cv.u & 0xFFFFE000u;
            unsigned slot = atomicAdd(&cnt[gr], 1u);
            if (slot < CAP) cand[gr * CAP + slot] = kb | (unsigned)colpt;
            if (band != seg) {
              int gc = b * NPTS + colpt;
              unsigned slot2 = atomicAdd(&cnt[gc], 1u);
              if (slot2 < CAP) cand[gc * CAP + slot2] = kb | (unsigned)rowpt;
            }
          }
        }
    }
  }
}

// ---------------- KT_self: cnt<=1 rows are fully decoupled (w_self=1 exactly) ----
// u <- lg - sigm(u), 5x. 64 blocks, massively parallel.
__global__ __launch_bounds__(256) void kt_self(
    const float* __restrict__ logits, const unsigned* __restrict__ cnt,
    float* __restrict__ out) {
  int i = blockIdx.x * 256 + threadIdx.x;   // 64 blocks -> 16384
  if (cnt[i] > 1u) return;
  float lg = logits[i];
  float u = lg;
#pragma unroll
  for (int it = 0; it < 5; ++it) u = lg - sigm(u);
  out[i] = sigm(u);
}

// ---------------- KT_multi: coupled subgraph (rows with cnt>1; graph is symmetric
// by mirror-capture, so all neighbors of multi rows are multi). 1 block, 512 thr:
// compact list -> thread-per-row refine (exact f32) -> 5 LDS iterations -> out.
__global__ __launch_bounds__(512) void kt_multi(
    const float* __restrict__ f32f, const float* __restrict__ sq,
    const unsigned* __restrict__ cnt, const unsigned* __restrict__ cand,
    float* __restrict__ Wbuf, int* __restrict__ IDXb,
    const float* __restrict__ logits, float* __restrict__ out) {
  __shared__ float qs[NTOT];                // 64 KB (indexed by global row)
  __shared__ int slist[MAXM];               // 32 KB
  __shared__ float su[MAXM];                // 32 KB
  __shared__ int sctr;
  int t = threadIdx.x;
  if (t == 0) sctr = 0;
  __syncthreads();

  // ---- build compact list of coupled rows ----
#pragma unroll 1
  for (int j = 0; j < 32; ++j) {
    int i = j * 512 + t;
    if (cnt[i] > 1u) {
      qs[i] = sigm(logits[i]);
      int slot = atomicAdd(&sctr, 1);
      if (slot < MAXM) slist[slot] = i;
    }
  }
  __syncthreads();
  int nm = sctr; if (nm > MAXM) nm = MAXM;

  // ---- refine: one thread per coupled row ----
#pragma unroll 1
  for (int k = t; k < nm; k += 512) {
    int r = slist[k];
    int bb = r >> 13;
    unsigned count = cnt[r]; if (count > CAP) count = CAP;
    unsigned kky[CAP];
#pragma unroll
    for (int jj = 0; jj < CAP; ++jj)
      kky[jj] = (jj < (int)count) ? cand[r * CAP + jj] : 0xFFFFFFFFu;
#pragma unroll
    for (int a = 0; a < CAP - 1; ++a)
#pragma unroll
      for (int cc = 0; cc < CAP - 1; ++cc) {
        unsigned lo = min(kky[cc], kky[cc + 1]);
        unsigned hi = max(kky[cc], kky[cc + 1]);
        kky[cc] = lo; kky[cc + 1] = hi;
      }
    float fr[64];
    const f32x4* fr4 = (const f32x4*)(f32f + (size_t)r * 64);
#pragma unroll
    for (int jj = 0; jj < 16; ++jj) {
      f32x4 v = fr4[jj];
      fr[4 * jj] = v[0]; fr[4 * jj + 1] = v[1]; fr[4 * jj + 2] = v[2]; fr[4 * jj + 3] = v[3];
    }
    float sqr = sq[r];
    int nsel = (int)count < KNB ? (int)count : KNB;
#pragma unroll 1
    for (int kk = 0; kk < KNB; ++kk) {
      float w = 0.f;
      int gi = r;
      if (kk < nsel) {
        int col = (int)(kky[kk] & 8191u);
        gi = bb * NPTS + col;
        const float* fm = f32f + (size_t)gi * 64;
        float dot = 0.f;
#pragma unroll
        for (int d = 0; d < 64; ++d) dot = fmaf(fr[d], fm[d], dot); // matches sq chain -> self d2==0
        float d2 = sqr + sq[gi] - 2.f * dot;
        w = expf(-d2);
      }
      Wbuf[(size_t)r * KNB + kk] = w;
      IDXb[(size_t)r * KNB + kk] = gi;
    }
  }
  __threadfence();
  __syncthreads();

  // ---- 5 mean-field iterations over the coupled subgraph ----
  for (int it = 0; it < 5; ++it) {
#pragma unroll 1
    for (int k = t; k < nm; k += 512) {
      int r = slist[k];
      float msg = 0.f;
      const float* wp = Wbuf + (size_t)r * KNB;
      const int* ip = IDXb + (size_t)r * KNB;
#pragma unroll
      for (int kk = 0; kk < KNB; ++kk) msg = fmaf(wp[kk], qs[ip[kk]], msg);
      su[k] = logits[r] - msg;
    }
    __syncthreads();
#pragma unroll 1
    for (int k = t; k < nm; k += 512) qs[slist[k]] = sigm(su[k]);
    __syncthreads();
  }
#pragma unroll 1
  for (int k = t; k < nm; k += 512) out[slist[k]] = sigm(su[k]);
}

// ---------------- launch ----------------
extern "C" void kernel_launch(void* const* d_in, const int* in_sizes, int n_in,
                              void* d_out, int out_size, void* d_ws, size_t ws_size,
                              hipStream_t stream) {
  const float* logits = (const float*)d_in[0]; // [2][8192]
  const float* p      = (const float*)d_in[1]; // [2][64][8192]
  const float* W1     = (const float*)d_in[2];
  const float* b1     = (const float*)d_in[3];
  const float* W2     = (const float*)d_in[4];
  const float* b2     = (const float*)d_in[5];
  float* out = (float*)d_out;                  // [2][8192]

  char* ws = (char*)d_ws;
  float* W12 = (float*)ws;                                         // 4096 f
  float* b12 = W12 + 4096;                                         // 64 f
  float* f32f = b12 + 64;                                          // NTOT*64 f
  unsigned short* fpre = (unsigned short*)(f32f + (size_t)NTOT * 64); // NTOT*32 bf16
  float* sq = (float*)(fpre + (size_t)NTOT * 32);                  // NTOT f
  float* sq32 = sq + NTOT;                                         // NTOT f
  unsigned* cnt = (unsigned*)(sq32 + NTOT);                        // NTOT u32
  unsigned* cand = cnt + NTOT;                                     // NTOT*CAP u32
  float* Wbuf = (float*)(cand + (size_t)NTOT * CAP);               // NTOT*11 f
  int* IDX = (int*)(Wbuf + (size_t)NTOT * KNB);                    // NTOT*11 i32

  k0_w12<<<64, 256, 0, stream>>>(W1, b1, W2, b2, W12, b12, cnt);
  k1_encode<<<256, 256, 0, stream>>>(p, W12, b12, f32f, fpre, sq, sq32);
  k2_gram_select<<<1056, 256, 0, stream>>>(fpre, sq32, cnt, cand);
  kt_self<<<64, 256, 0, stream>>>(logits, cnt, out);
  kt_multi<<<1, 512, 0, stream>>>(f32f, sq, cnt, cand, Wbuf, IDX, logits, out);
}

// Round 9
// 115.984 us; speedup vs baseline: 1.2484x; 1.0776x over previous
//
#include <hip/hip_runtime.h>

#define NPTS 8192
#define NTOT 16384
#define KNB 11
#define CAP 16
#define MARG 9.0f
#define MAXM 8192

typedef __attribute__((ext_vector_type(8))) short short8;
typedef __attribute__((ext_vector_type(4))) float f32x4;

__device__ __forceinline__ unsigned short f2bf(float x) {
  union { float f; unsigned u; } v; v.f = x;
  unsigned r = v.u + 0x7FFFu + ((v.u >> 16) & 1u);
  return (unsigned short)(r >> 16);
}

__device__ __forceinline__ float sigm(float x) { return 1.f / (1.f + expf(-x)); }

// ---------------- K0: W12 = W1*W2, b12 = b1*W2 + b2 ; zero cnt ----------------
__global__ __launch_bounds__(256) void k0_w12(
    const float* __restrict__ W1, const float* __restrict__ b1,
    const float* __restrict__ W2, const float* __restrict__ b2,
    float* __restrict__ W12, float* __restrict__ b12,
    unsigned* __restrict__ cnt) {
  int t = blockIdx.x * 256 + threadIdx.x;   // 64 blocks -> 16384
  cnt[t] = 0u;
  if (t >= 4096) return;
  int d = t >> 6, e = t & 63;
  float s = 0.f;
  for (int kk = 0; kk < 64; ++kk) s = fmaf(W1[d * 64 + kk], W2[kk * 64 + e], s);
  W12[t] = s;
  if (d == 0) {
    float sb = b2[e];
    for (int kk = 0; kk < 64; ++kk) sb = fmaf(b1[kk], W2[kk * 64 + e], sb);
    b12[e] = sb;
  }
}

// ---------------- K1: f = p^T*W12 + b12 ; sq/sq32 ; bf16 prefilter copy ----------------
// 256 blocks x 256 threads: 64 points/block, wave w handles dims e0=w*16..+16.
// p tile staged in LDS (coalesced); W12 via wave-uniform offset -> s_load path.
__global__ __launch_bounds__(256) void k1_encode(
    const float* __restrict__ p,      // [2][64][NPTS]
    const float* __restrict__ W12,    // [64][64]
    const float* __restrict__ b12,    // [64]
    float* __restrict__ f32f,         // [NTOT][64]
    unsigned short* __restrict__ fpre,// [NTOT][32] bf16 (dims 0..31)
    float* __restrict__ sq,           // [NTOT] full 64-dim |f|^2
    float* __restrict__ sq32) {       // [NTOT] dims 0..31 |f|^2
  __shared__ float sp[64 * 64];       // 16 KB: sp[d*64 + n_local]
  __shared__ float sPart[4][64];
  int t = threadIdx.x, lane = t & 63;
  int w = __builtin_amdgcn_readfirstlane(t >> 6);
  int e0 = w * 16;                          // wave-uniform -> scalar loads
  int base = blockIdx.x * 64;
  int b = base >> 13, n0 = base & (NPTS - 1);
  const float* pb = p + (size_t)b * 64 * NPTS + n0;

  // stage p tile: 64 d-rows x 64 points, coalesced uint4
  int row = t >> 4, chunk = t & 15;
#pragma unroll
  for (int k = 0; k < 4; ++k) {
    int r = k * 16 + row;
    uint4 v = *(const uint4*)(pb + (size_t)r * NPTS + chunk * 4);
    *(uint4*)(sp + r * 64 + chunk * 4) = v;
  }
  __syncthreads();

  float f[16];
#pragma unroll
  for (int j = 0; j < 16; ++j) f[j] = b12[e0 + j];

#pragma unroll 8
  for (int d = 0; d < 64; ++d) {
    float pd = sp[d * 64 + lane];
#pragma unroll
    for (int j = 0; j < 16; ++j)
      f[j] = fmaf(pd, W12[d * 64 + e0 + j], f[j]);
  }

  float s = 0.f;
#pragma unroll
  for (int j = 0; j < 16; ++j) s = fmaf(f[j], f[j], s);
  sPart[w][lane] = s;
  __syncthreads();
  if (w == 0) {
    float s32 = sPart[0][lane] + sPart[1][lane];
    float s64 = s32 + (sPart[2][lane] + sPart[3][lane]);
    sq32[base + lane] = s32;
    sq[base + lane] = s64;
  }

  f32x4* o4 = (f32x4*)(f32f + (size_t)(base + lane) * 64 + e0);
#pragma unroll
  for (int jj = 0; jj < 4; ++jj) {
    f32x4 v; v[0] = f[4 * jj]; v[1] = f[4 * jj + 1]; v[2] = f[4 * jj + 2]; v[3] = f[4 * jj + 3];
    o4[jj] = v;
  }
  if (w < 2) {                               // dims 0..31 -> bf16 prefilter
    unsigned* ob = (unsigned*)(fpre + (size_t)(base + lane) * 32 + e0);
#pragma unroll
    for (int jj = 0; jj < 8; ++jj) {
      unsigned lo = f2bf(f[2 * jj]);
      unsigned hi = f2bf(f[2 * jj + 1]);
      ob[jj] = lo | (hi << 16);
    }
  }
}

// ---------------- K2: 32-dim prefilter Gram, triangle-symmetric ----
// 1056 blocks = 2 x 528 (lower-triangle incl diag of 32x32 256-blocks).
// Hot: per tile 1 ds_read + 4 MFMA + EXACT per-row/col margin test -> SGPR hitmask.
// Cold (once, after loop): recompute only hit tiles (diag: 4/16; off-diag: ~never).
__global__ __launch_bounds__(256) void k2_gram_select(
    const unsigned short* __restrict__ fpre, // [NTOT][32]
    const float* __restrict__ sq32,          // [NTOT]
    unsigned* __restrict__ cnt,              // [NTOT]
    unsigned* __restrict__ cand) {           // [NTOT][CAP]
  __shared__ uint4 sB[1024];                 // 16 KB panel, XOR-swizzled
  int bid = blockIdx.x;
  int b = (bid >= 528) ? 1 : 0;
  int rem = bid - b * 528;
  int band = (int)((sqrtf(8.f * (float)rem + 1.f) - 1.f) * 0.5f);
  if (((band + 1) * (band + 2)) / 2 <= rem) band++;
  else if ((band * (band + 1)) / 2 > rem) band--;
  int seg = rem - (band * (band + 1)) / 2;

  int t = threadIdx.x;
  int lane = t & 63;
  int arow = lane & 15;
  int q = lane >> 4;
  int wave = t >> 6;
  int rowbase = band * 256 + wave * 64;
  int cbase = seg * 256;
  const unsigned short* fb = fpre + (size_t)b * NPTS * 32;
  const float* s32b = sq32 + b * NPTS;

  // ---- prologue: all global loads, then ONE barrier ----
  const uint4* gsrc = (const uint4*)fb + (size_t)seg * 1024;
  uint4 v[4];
#pragma unroll
  for (int k = 0; k < 4; ++k) v[k] = gsrc[t + k * 256];

  short8 afrag[4];
#pragma unroll
  for (int tr = 0; tr < 4; ++tr)
    afrag[tr] = *(const short8*)(fb + (size_t)(rowbase + tr * 16 + arow) * 32 + q * 8);

  f32x4 srq[4], hh[4];
#pragma unroll
  for (int tr = 0; tr < 4; ++tr) {
    srq[tr] = *(const f32x4*)(s32b + rowbase + tr * 16 + (q << 2));
    hh[tr] = 0.5f * srq[tr];
  }
  float thrc[16];                            // per-lane column threshold
#pragma unroll
  for (int cc = 0; cc < 4; ++cc)
#pragma unroll
    for (int tc = 0; tc < 4; ++tc)
      thrc[cc * 4 + tc] = 0.5f * s32b[cbase + cc * 64 + tc * 16 + arow] - 0.5f * MARG;

#pragma unroll
  for (int k = 0; k < 4; ++k) {
    int c = t + k * 256;
    int r = c >> 2, qq = c & 3;
    sB[r * 4 + (qq ^ (r & 3))] = v[k];
  }
  __syncthreads();   // the ONLY barrier

  // ---- hot pass: MFMA + exact margin test, hit tiles -> SGPR mask ----
  f32x4 z4 = {0.f, 0.f, 0.f, 0.f};
  unsigned hitmask = 0u;
#pragma unroll
  for (int cc = 0; cc < 4; ++cc)
#pragma unroll
    for (int tc = 0; tc < 4; ++tc) {
      int e = cc * 4 + tc;
      int rl = cc * 64 + tc * 16 + arow;
      short8 bf = *(const short8*)&sB[rl * 4 + (q ^ (rl & 3))];
      f32x4 a0 = __builtin_amdgcn_mfma_f32_16x16x32_bf16(afrag[0], bf, z4, 0, 0, 0);
      f32x4 a1 = __builtin_amdgcn_mfma_f32_16x16x32_bf16(afrag[1], bf, z4, 0, 0, 0);
      f32x4 a2 = __builtin_amdgcn_mfma_f32_16x16x32_bf16(afrag[2], bf, z4, 0, 0, 0);
      f32x4 a3 = __builtin_amdgcn_mfma_f32_16x16x32_bf16(afrag[3], bf, z4, 0, 0, 0);
      // exact: exists row with a - 0.5*sq_row > 0.5*sq_col - MARG/2  <=>  d2_32 < MARG
      float m0 = fmaxf(fmaxf(a0[0] - hh[0][0], a0[1] - hh[0][1]),
                       fmaxf(a0[2] - hh[0][2], a0[3] - hh[0][3]));
      float m1 = fmaxf(fmaxf(a1[0] - hh[1][0], a1[1] - hh[1][1]),
                       fmaxf(a1[2] - hh[1][2], a1[3] - hh[1][3]));
      float m2 = fmaxf(fmaxf(a2[0] - hh[2][0], a2[1] - hh[2][1]),
                       fmaxf(a2[2] - hh[2][2], a2[3] - hh[2][3]));
      float m3 = fmaxf(fmaxf(a3[0] - hh[3][0], a3[1] - hh[3][1]),
                       fmaxf(a3[2] - hh[3][2], a3[3] - hh[3][3]));
      float m = fmaxf(fmaxf(m0, m1), fmaxf(m2, m3));
      if (__ballot(m > thrc[e])) hitmask |= (1u << e);
    }

  // ---- cold: only hit tiles (compact, single copy of capture code) ----
  if (hitmask) {
#pragma unroll 1
    for (int e = 0; e < 16; ++e) {
      if (!(hitmask & (1u << e))) continue;
      int cc = e >> 2, tc = e & 3;
      int rl = cc * 64 + tc * 16 + arow;
      short8 bf = *(const short8*)&sB[rl * 4 + (q ^ (rl & 3))];
      int colpt = cbase + cc * 64 + tc * 16 + arow;
      float scv = s32b[colpt];
      f32x4 acc[4];
#pragma unroll
      for (int tr = 0; tr < 4; ++tr)
        acc[tr] = __builtin_amdgcn_mfma_f32_16x16x32_bf16(afrag[tr], bf, z4, 0, 0, 0);
#pragma unroll
      for (int tr = 0; tr < 4; ++tr)
#pragma unroll
        for (int rg = 0; rg < 4; ++rg) {
          float d2 = srq[tr][rg] + scv - 2.f * acc[tr][rg];
          if (d2 < MARG) {
            int rowpt = rowbase + tr * 16 + (q << 2) + rg;
            int gr = b * NPTS + rowpt;
            union { float f; unsigned u; } cv; cv.f = d2 + 16.f;  // monotone bits
            unsigned kb = cv.u & 0xFFFFE000u;
            unsigned slot = atomicAdd(&cnt[gr], 1u);
            if (slot < CAP) cand[gr * CAP + slot] = kb | (unsigned)colpt;
            if (band != seg) {
              int gc = b * NPTS + colpt;
              unsigned slot2 = atomicAdd(&cnt[gc], 1u);
              if (slot2 < CAP) cand[gc * CAP + slot2] = kb | (unsigned)rowpt;
            }
          }
        }
    }
  }
}

// ---------------- K3_fused: decoupled rows -> final out ; coupled rows -> refine ----
// 64 blocks x 256. cnt<=1: u <- lg - sigm(u) (w_self=1 exactly), 5x, write out, done.
// cnt>1 (~300 rows): sort candidates, exact-f32 d2, write Wbuf/IDX for kt_iter.
__global__ __launch_bounds__(256) void k3_fused(
    const float* __restrict__ f32f, const float* __restrict__ sq,
    const unsigned* __restrict__ cnt, const unsigned* __restrict__ cand,
    float* __restrict__ Wbuf, int* __restrict__ IDXb,
    const float* __restrict__ logits, float* __restrict__ out) {
  int r = blockIdx.x * 256 + threadIdx.x;
  int b = r >> 13;
  unsigned count = cnt[r];
  if (count <= 1u) {
    float lg = logits[r];
    float u = lg;
#pragma unroll
    for (int it = 0; it < 5; ++it) u = lg - sigm(u);
    out[r] = sigm(u);
    return;
  }
  if (count > CAP) count = CAP;

  unsigned k[CAP];
#pragma unroll
  for (int j = 0; j < CAP; ++j)
    k[j] = (j < (int)count) ? cand[r * CAP + j] : 0xFFFFFFFFu;
#pragma unroll
  for (int a = 0; a < CAP - 1; ++a)
#pragma unroll
    for (int c = 0; c < CAP - 1; ++c) {
      unsigned lo = min(k[c], k[c + 1]);
      unsigned hi = max(k[c], k[c + 1]);
      k[c] = lo; k[c + 1] = hi;
    }

  float fr[64];
  const f32x4* fr4 = (const f32x4*)(f32f + (size_t)r * 64);
#pragma unroll
  for (int j = 0; j < 16; ++j) {
    f32x4 v = fr4[j];
    fr[4 * j] = v[0]; fr[4 * j + 1] = v[1]; fr[4 * j + 2] = v[2]; fr[4 * j + 3] = v[3];
  }
  float sqr = sq[r];
  int nsel = (int)count < KNB ? (int)count : KNB;
#pragma unroll
  for (int kk = 0; kk < KNB; ++kk) {
    float w = 0.f;
    int gi = r;
    if (kk < nsel) {
      int col = (int)(k[kk] & 8191u);
      gi = b * NPTS + col;
      const float* fm = f32f + (size_t)gi * 64;
      float dot = 0.f;
#pragma unroll
      for (int d = 0; d < 64; ++d) dot = fmaf(fr[d], fm[d], dot); // matches sq chain -> self d2==0
      float d2 = sqr + sq[gi] - 2.f * dot;
      w = expf(-d2);
    }
    Wbuf[(size_t)r * KNB + kk] = w;
    IDXb[(size_t)r * KNB + kk] = gi;
  }
}

// ---------------- KT_iter: 5 coupled iterations over the ~300-row subgraph ----
// Graph is symmetric (mirror capture) => neighbors of coupled rows are coupled.
// 1 block x 1024; qs in LDS indexed by global row; W/IDX L2-hot.
__global__ __launch_bounds__(1024) void kt_iter(
    const unsigned* __restrict__ cnt,
    const float* __restrict__ Wbuf, const int* __restrict__ IDXb,
    const float* __restrict__ logits, float* __restrict__ out) {
  __shared__ float qs[NTOT];                // 64 KB (indexed by global row)
  __shared__ int slist[MAXM];               // 32 KB
  __shared__ float su[MAXM];                // 32 KB
  __shared__ int sctr;
  int t = threadIdx.x;
  if (t == 0) sctr = 0;
  __syncthreads();

#pragma unroll 1
  for (int j = 0; j < 16; ++j) {
    int i = j * 1024 + t;
    if (cnt[i] > 1u) {
      qs[i] = sigm(logits[i]);
      int slot = atomicAdd(&sctr, 1);
      if (slot < MAXM) slist[slot] = i;
    }
  }
  __syncthreads();
  int nm = sctr; if (nm > MAXM) nm = MAXM;

  for (int it = 0; it < 5; ++it) {
#pragma unroll 1
    for (int k = t; k < nm; k += 1024) {
      int r = slist[k];
      float msg = 0.f;
      const float* wp = Wbuf + (size_t)r * KNB;
      const int* ip = IDXb + (size_t)r * KNB;
#pragma unroll
      for (int kk = 0; kk < KNB; ++kk) msg = fmaf(wp[kk], qs[ip[kk]], msg);
      su[k] = logits[r] - msg;
    }
    __syncthreads();
#pragma unroll 1
    for (int k = t; k < nm; k += 1024) qs[slist[k]] = sigm(su[k]);
    __syncthreads();
  }
#pragma unroll 1
  for (int k = t; k < nm; k += 1024) out[slist[k]] = sigm(su[k]);
}

// ---------------- launch ----------------
extern "C" void kernel_launch(void* const* d_in, const int* in_sizes, int n_in,
                              void* d_out, int out_size, void* d_ws, size_t ws_size,
                              hipStream_t stream) {
  const float* logits = (const float*)d_in[0]; // [2][8192]
  const float* p      = (const float*)d_in[1]; // [2][64][8192]
  const float* W1     = (const float*)d_in[2];
  const float* b1     = (const float*)d_in[3];
  const float* W2     = (const float*)d_in[4];
  const float* b2     = (const float*)d_in[5];
  float* out = (float*)d_out;                  // [2][8192]

  char* ws = (char*)d_ws;
  float* W12 = (float*)ws;                                         // 4096 f
  float* b12 = W12 + 4096;                                         // 64 f
  float* f32f = b12 + 64;                                          // NTOT*64 f
  unsigned short* fpre = (unsigned short*)(f32f + (size_t)NTOT * 64); // NTOT*32 bf16
  float* sq = (float*)(fpre + (size_t)NTOT * 32);                  // NTOT f
  float* sq32 = sq + NTOT;                                         // NTOT f
  unsigned* cnt = (unsigned*)(sq32 + NTOT);                        // NTOT u32
  unsigned* cand = cnt + NTOT;                                     // NTOT*CAP u32
  float* Wbuf = (float*)(cand + (size_t)NTOT * CAP);               // NTOT*11 f
  int* IDX = (int*)(Wbuf + (size_t)NTOT * KNB);                    // NTOT*11 i32

  k0_w12<<<64, 256, 0, stream>>>(W1, b1, W2, b2, W12, b12, cnt);
  k1_encode<<<256, 256, 0, stream>>>(p, W12, b12, f32f, fpre, sq, sq32);
  k2_gram_select<<<1056, 256, 0, stream>>>(fpre, sq32, cnt, cand);
  k3_fused<<<64, 256, 0, stream>>>(f32f, sq, cnt, cand, Wbuf, IDX, logits, out);
  kt_iter<<<1, 1024, 0, stream>>>(cnt, Wbuf, IDX, logits, out);
}